// Round 3
// baseline (194.850 us; speedup 1.0000x reference)
//
#include <hip/hip_runtime.h>
#include <hip/hip_cooperative_groups.h>

namespace cg = cooperative_groups;

// ---------------------------------------------------------------------------
// HybridNN, fused single cooperative kernel.
// Phase 1: blocks 0..255 tabulate y = F(u0,u1) on a 256x256 grid into d_ws
//          (1 circuit eval per thread).  F depends only on the two layer-2
//          pre-activations u0,u1; range [-B,B] with B = sum|w2|+|b2| provable.
// grid.sync()
// Phase 2: all 1024 blocks x 256 threads evaluate 4 samples each:
//          MLP layer 1 (4 tanh) -> (u0,u1) -> bilinear table lookup.
// ---------------------------------------------------------------------------

#define TN 256          // table points per dimension (256 KB in d_ws)
#define NBLOCKS 1024
#define NTHREADS 256

struct c2 { float re, im; };

__device__ __forceinline__ c2 cmul(c2 a, c2 b) {
    c2 r;
    r.re = fmaf(a.re, b.re, -(a.im * b.im));
    r.im = fmaf(a.re, b.im, a.im * b.re);
    return r;
}

__device__ __forceinline__ c2 cfma(c2 a, c2 b, c2 acc) {
    acc.re = fmaf(a.re, b.re, fmaf(-a.im, b.im, acc.re));
    acc.im = fmaf(a.re, b.im, fmaf(a.im, b.re, acc.im));
    return acc;
}

__device__ __forceinline__ void rx_pair(c2& u, c2& v, float c, float s) {
    c2 nu, nv;
    nu.re = fmaf(c, u.re,  s * v.im);
    nu.im = fmaf(c, u.im, -(s * v.re));
    nv.re = fmaf(c, v.re,  s * u.im);
    nv.im = fmaf(c, v.im, -(s * u.re));
    u = nu; v = nv;
}

__device__ __forceinline__ void rot_pair(c2& u, c2& v, c2 g00, c2 g01, c2 g10, c2 g11) {
    c2 nu = cmul(g00, u); nu = cfma(g01, v, nu);
    c2 nv = cmul(g10, u); nv = cfma(g11, v, nv);
    u = nu; v = nv;
}

__device__ __forceinline__ float ftanh(float v) {
    float e = __expf(2.0f * v);
    return __fdividef(e - 1.0f, e + 1.0f);
}

__device__ __forceinline__ void u_bounds(const float* w2, const float* b2,
                                         float& B0, float& B1) {
    B0 = fabsf(w2[0]) + fabsf(w2[1]) + fabsf(w2[2]) + fabsf(w2[3]) + fabsf(b2[0]);
    B1 = fabsf(w2[4]) + fabsf(w2[5]) + fabsf(w2[6]) + fabsf(w2[7]) + fabsf(b2[1]);
}

__device__ __forceinline__ float circuit_y(float g0, float g1,
                                           const float (*Rs)[2][8],
                                           float pw0, float pw1, float pb) {
    float cs0 = __cosf(0.5f * g0), sn0 = __sinf(0.5f * g0);
    float cs1 = __cosf(0.5f * g1), sn1 = __sinf(0.5f * g1);

    c2 s00 = {1.0f, 0.0f}, s01 = {0.0f, 0.0f};
    c2 s10 = {0.0f, 0.0f}, s11 = {0.0f, 0.0f};

#pragma unroll
    for (int l = 0; l < 4; l++) {
        rx_pair(s00, s10, cs0, sn0);
        rx_pair(s01, s11, cs0, sn0);
        rx_pair(s00, s01, cs1, sn1);
        rx_pair(s10, s11, cs1, sn1);
        {
            const float* r = Rs[l][0];
            c2 g00 = {r[0], r[1]}, g01 = {r[2], r[3]};
            c2 g10 = {r[4], r[5]}, g11 = {r[6], r[7]};
            rot_pair(s00, s10, g00, g01, g10, g11);
            rot_pair(s01, s11, g00, g01, g10, g11);
        }
        {
            const float* r = Rs[l][1];
            c2 g00 = {r[0], r[1]}, g01 = {r[2], r[3]};
            c2 g10 = {r[4], r[5]}, g11 = {r[6], r[7]};
            rot_pair(s00, s01, g00, g01, g10, g11);
            rot_pair(s10, s11, g00, g01, g10, g11);
        }
        { c2 tmp = s10; s10 = s11; s11 = tmp; }  // CNOT(0,1)
        { c2 tmp = s01; s01 = s11; s11 = tmp; }  // CNOT(1,0)
    }

    float p00 = fmaf(s00.re, s00.re, s00.im * s00.im);
    float p01 = fmaf(s01.re, s01.re, s01.im * s01.im);
    float p10 = fmaf(s10.re, s10.re, s10.im * s10.im);
    float p11 = fmaf(s11.re, s11.re, s11.im * s11.im);
    float z0 = (p00 + p01) - (p10 + p11);
    float z1 = (p00 + p10) - (p01 + p11);

    float q0 = 0.5f * (z0 + 1.0f);
    float q1 = 0.5f * (z1 + 1.0f);
    float y  = fmaf(pw0, q0, fmaf(pw1, q1, pb));
    return __fdividef(1.0f, 1.0f + __expf(-y));
}

__global__ __launch_bounds__(NTHREADS, 4) void fused_kernel(
    const float* __restrict__ x,       // (B,2)
    const float* __restrict__ pre_w1,  // (4,2)
    const float* __restrict__ pre_b1,  // (4,)
    const float* __restrict__ pre_w2,  // (2,4)
    const float* __restrict__ pre_b2,  // (2,)
    const float* __restrict__ qw,      // (4,2,3)
    const float* __restrict__ post_w,  // (1,2)
    const float* __restrict__ post_b,  // (1,)
    float* __restrict__ table,         // (TN*TN,) in d_ws
    float* __restrict__ out,           // (B,)
    int nbatch)
{
    int tid = threadIdx.x;
    int bid = blockIdx.x;

    float B0, B1;
    u_bounds(pre_w2, pre_b2, B0, B1);

    // ---------------- Phase 1: table build (blocks 0..TN*TN/NTHREADS-1) ----
    if (bid < (TN * TN) / NTHREADS) {
        __shared__ float Rs[4][2][8];
        if (tid < 8) {
            int l = tid >> 1, w = tid & 1;
            const float* p = qw + (l * 2 + w) * 3;
            float phi = p[0], th = p[1], om = p[2];
            float c  = cosf(0.5f * th), s = sinf(0.5f * th);
            float a  = 0.5f * (phi + om), b = 0.5f * (phi - om);
            float ca = cosf(a), sa = sinf(a);
            float cb = cosf(b), sb = sinf(b);
            float* r = Rs[l][w];
            r[0] =  c * ca;  r[1] = -c * sa;   // g00
            r[2] = -s * cb;  r[3] = -s * sb;   // g01
            r[4] =  s * cb;  r[5] = -s * sb;   // g10
            r[6] =  c * ca;  r[7] =  c * sa;   // g11
        }
        __syncthreads();

        int k = bid * NTHREADS + tid;
        int i = k & (TN - 1);
        int j = k >> 8;
        float u0 = fmaf((2.0f * B0) / (float)(TN - 1), (float)i, -B0);
        float u1 = fmaf((2.0f * B1) / (float)(TN - 1), (float)j, -B1);
        table[k] = circuit_y(ftanh(u0), ftanh(u1), Rs,
                             post_w[0], post_w[1], post_b[0]);
    }

    cg::this_grid().sync();

    // ---------------- Phase 2: per-sample eval, 4 samples/thread -----------
    float w1[8], b1[4], w2[8], b2[2];
#pragma unroll
    for (int i = 0; i < 8; i++) w1[i] = pre_w1[i];
#pragma unroll
    for (int i = 0; i < 4; i++) b1[i] = pre_b1[i];
#pragma unroll
    for (int i = 0; i < 8; i++) w2[i] = pre_w2[i];
#pragma unroll
    for (int i = 0; i < 2; i++) b2[i] = pre_b2[i];

    float sc0 = (float)(TN - 1) / (2.0f * B0);
    float sc1 = (float)(TN - 1) / (2.0f * B1);

    int base = (bid * NTHREADS + tid) * 4;   // 4 samples per thread
    if (base >= nbatch) return;

    float4 xa = *reinterpret_cast<const float4*>(x + 2 * (long long)base);
    float4 xb = *reinterpret_cast<const float4*>(x + 2 * (long long)base + 4);
    float xs0[4] = { xa.x, xa.z, xb.x, xb.z };
    float xs1[4] = { xa.y, xa.w, xb.y, xb.w };
    float res[4];

#pragma unroll
    for (int t = 0; t < 4; t++) {
        float x0 = xs0[t], x1 = xs1[t];

        float h0 = ftanh(fmaf(w1[0], x0, fmaf(w1[1], x1, b1[0])));
        float h1 = ftanh(fmaf(w1[2], x0, fmaf(w1[3], x1, b1[1])));
        float h2 = ftanh(fmaf(w1[4], x0, fmaf(w1[5], x1, b1[2])));
        float h3 = ftanh(fmaf(w1[6], x0, fmaf(w1[7], x1, b1[3])));

        float u0 = fmaf(w2[0], h0, fmaf(w2[1], h1, fmaf(w2[2], h2, fmaf(w2[3], h3, b2[0]))));
        float u1 = fmaf(w2[4], h0, fmaf(w2[5], h1, fmaf(w2[6], h2, fmaf(w2[7], h3, b2[1]))));

        float t0 = (u0 + B0) * sc0;
        float t1 = (u1 + B1) * sc1;
        t0 = fminf(fmaxf(t0, 0.0f), (float)(TN - 1));
        t1 = fminf(fmaxf(t1, 0.0f), (float)(TN - 1));
        float i0f = fminf(floorf(t0), (float)(TN - 2));
        float j0f = fminf(floorf(t1), (float)(TN - 2));
        float f0 = t0 - i0f;
        float f1 = t1 - j0f;
        int i0 = (int)i0f;
        int j0 = (int)j0f;

        const float* p = table + j0 * TN + i0;
        float a = p[0], b = p[1], c = p[TN], d = p[TN + 1];
        float top = fmaf(f0, b - a, a);
        float bot = fmaf(f0, d - c, c);
        res[t] = fmaf(f1, bot - top, top);
    }

    *reinterpret_cast<float4*>(out + base) = make_float4(res[0], res[1], res[2], res[3]);
}

extern "C" void kernel_launch(void* const* d_in, const int* in_sizes, int n_in,
                              void* d_out, int out_size, void* d_ws, size_t ws_size,
                              hipStream_t stream) {
    const float* x      = (const float*)d_in[0];
    const float* pre_w1 = (const float*)d_in[1];
    const float* pre_b1 = (const float*)d_in[2];
    const float* pre_w2 = (const float*)d_in[3];
    const float* pre_b2 = (const float*)d_in[4];
    const float* qw     = (const float*)d_in[5];
    const float* post_w = (const float*)d_in[6];
    const float* post_b = (const float*)d_in[7];
    float* out   = (float*)d_out;
    float* table = (float*)d_ws;   // TN*TN floats = 256 KB
    int nbatch   = in_sizes[0] / 2;

    void* args[] = {
        (void*)&x, (void*)&pre_w1, (void*)&pre_b1, (void*)&pre_w2, (void*)&pre_b2,
        (void*)&qw, (void*)&post_w, (void*)&post_b, (void*)&table, (void*)&out,
        (void*)&nbatch,
    };
    hipLaunchCooperativeKernel((const void*)fused_kernel,
                               dim3(NBLOCKS), dim3(NTHREADS),
                               args, 0, stream);
}

// Round 5
// 78.002 us; speedup vs baseline: 2.4980x; 2.4980x over previous
//
#include <hip/hip_runtime.h>

// ---------------------------------------------------------------------------
// HybridNN via 2-D lookup table (two ordinary launches — cooperative grid
// sync measured at ~100us on MI355X in R3, 20x worse than a 2nd dispatch).
// Insight: network output y depends ONLY on the two layer-2 pre-activations
// (u0,u1) (g = tanh(u) feeds the quantum circuit + post-net).
// Kernel 1: tabulate y = F(u0,u1), 128x128 grid over provable range [-B,B],
//           B = sum|w2|+|b2|.  64 KB table in d_ws, L2-resident.
// Kernel 2: MLP layer 1 + bilinear lookup, 4 samples/thread.
// ---------------------------------------------------------------------------

#define TN 128   // table points per dimension (64 KB table)

typedef float vfloat4 __attribute__((ext_vector_type(4)));  // clang vector (builtin-compatible)

struct c2 { float re, im; };

__device__ __forceinline__ c2 cmul(c2 a, c2 b) {
    c2 r;
    r.re = fmaf(a.re, b.re, -(a.im * b.im));
    r.im = fmaf(a.re, b.im, a.im * b.re);
    return r;
}

__device__ __forceinline__ c2 cfma(c2 a, c2 b, c2 acc) {
    acc.re = fmaf(a.re, b.re, fmaf(-a.im, b.im, acc.re));
    acc.im = fmaf(a.re, b.im, fmaf(a.im, b.re, acc.im));
    return acc;
}

__device__ __forceinline__ void rx_pair(c2& u, c2& v, float c, float s) {
    c2 nu, nv;
    nu.re = fmaf(c, u.re,  s * v.im);
    nu.im = fmaf(c, u.im, -(s * v.re));
    nv.re = fmaf(c, v.re,  s * u.im);
    nv.im = fmaf(c, v.im, -(s * u.re));
    u = nu; v = nv;
}

__device__ __forceinline__ void rot_pair(c2& u, c2& v, c2 g00, c2 g01, c2 g10, c2 g11) {
    c2 nu = cmul(g00, u); nu = cfma(g01, v, nu);
    c2 nv = cmul(g10, u); nv = cfma(g11, v, nv);
    u = nu; v = nv;
}

__device__ __forceinline__ float ftanh(float v) {
    float e = __expf(2.0f * v);
    return __fdividef(e - 1.0f, e + 1.0f);
}

// u-range bounds; MUST be computed identically in both kernels.
__device__ __forceinline__ void u_bounds(const float* w2, const float* b2,
                                         float& B0, float& B1) {
    B0 = fabsf(w2[0]) + fabsf(w2[1]) + fabsf(w2[2]) + fabsf(w2[3]) + fabsf(b2[0]);
    B1 = fabsf(w2[4]) + fabsf(w2[5]) + fabsf(w2[6]) + fabsf(w2[7]) + fabsf(b2[1]);
}

__device__ __forceinline__ float circuit_y(float g0, float g1,
                                           const float (*Rs)[2][8],
                                           float pw0, float pw1, float pb) {
    float cs0 = __cosf(0.5f * g0), sn0 = __sinf(0.5f * g0);
    float cs1 = __cosf(0.5f * g1), sn1 = __sinf(0.5f * g1);

    c2 s00 = {1.0f, 0.0f}, s01 = {0.0f, 0.0f};
    c2 s10 = {0.0f, 0.0f}, s11 = {0.0f, 0.0f};

#pragma unroll
    for (int l = 0; l < 4; l++) {
        rx_pair(s00, s10, cs0, sn0);
        rx_pair(s01, s11, cs0, sn0);
        rx_pair(s00, s01, cs1, sn1);
        rx_pair(s10, s11, cs1, sn1);
        {
            const float* r = Rs[l][0];
            c2 g00 = {r[0], r[1]}, g01 = {r[2], r[3]};
            c2 g10 = {r[4], r[5]}, g11 = {r[6], r[7]};
            rot_pair(s00, s10, g00, g01, g10, g11);
            rot_pair(s01, s11, g00, g01, g10, g11);
        }
        {
            const float* r = Rs[l][1];
            c2 g00 = {r[0], r[1]}, g01 = {r[2], r[3]};
            c2 g10 = {r[4], r[5]}, g11 = {r[6], r[7]};
            rot_pair(s00, s01, g00, g01, g10, g11);
            rot_pair(s10, s11, g00, g01, g10, g11);
        }
        { c2 tmp = s10; s10 = s11; s11 = tmp; }  // CNOT(0,1)
        { c2 tmp = s01; s01 = s11; s11 = tmp; }  // CNOT(1,0)
    }

    float p00 = fmaf(s00.re, s00.re, s00.im * s00.im);
    float p01 = fmaf(s01.re, s01.re, s01.im * s01.im);
    float p10 = fmaf(s10.re, s10.re, s10.im * s10.im);
    float p11 = fmaf(s11.re, s11.re, s11.im * s11.im);
    float z0 = (p00 + p01) - (p10 + p11);
    float z1 = (p00 + p10) - (p01 + p11);

    float q0 = 0.5f * (z0 + 1.0f);
    float q1 = 0.5f * (z1 + 1.0f);
    float y  = fmaf(pw0, q0, fmaf(pw1, q1, pb));
    return __fdividef(1.0f, 1.0f + __expf(-y));
}

// ---------------------------------------------------------------------------
// Kernel 1: tabulate y = F(u0,u1), TNxTN grid.  TN*TN/256 blocks.
// ---------------------------------------------------------------------------
__global__ __launch_bounds__(256) void build_table(
    const float* __restrict__ qw,      // (4,2,3)
    const float* __restrict__ pre_w2,  // (2,4)
    const float* __restrict__ pre_b2,  // (2,)
    const float* __restrict__ post_w,  // (1,2)
    const float* __restrict__ post_b,  // (1,)
    float* __restrict__ table)         // (TN*TN,)
{
    __shared__ float Rs[4][2][8];
    int tid = threadIdx.x;
    if (tid < 8) {
        int l = tid >> 1, w = tid & 1;
        const float* p = qw + (l * 2 + w) * 3;
        float phi = p[0], th = p[1], om = p[2];
        float c  = cosf(0.5f * th), s = sinf(0.5f * th);
        float a  = 0.5f * (phi + om), b = 0.5f * (phi - om);
        float ca = cosf(a), sa = sinf(a);
        float cb = cosf(b), sb = sinf(b);
        float* r = Rs[l][w];
        r[0] =  c * ca;  r[1] = -c * sa;   // g00
        r[2] = -s * cb;  r[3] = -s * sb;   // g01
        r[4] =  s * cb;  r[5] = -s * sb;   // g10
        r[6] =  c * ca;  r[7] =  c * sa;   // g11
    }
    __syncthreads();

    int k = blockIdx.x * 256 + tid;
    int i = k & (TN - 1);
    int j = k / TN;

    float B0, B1;
    u_bounds(pre_w2, pre_b2, B0, B1);

    float u0 = fmaf((2.0f * B0) / (float)(TN - 1), (float)i, -B0);
    float u1 = fmaf((2.0f * B1) / (float)(TN - 1), (float)j, -B1);

    table[k] = circuit_y(ftanh(u0), ftanh(u1), Rs,
                         post_w[0], post_w[1], post_b[0]);
}

// ---------------------------------------------------------------------------
// Kernel 2: MLP layer 1 + bilinear table lookup. 4 samples/thread.
// ---------------------------------------------------------------------------
__global__ __launch_bounds__(256) void eval_kernel(
    const float* __restrict__ x,       // (B,2)
    const float* __restrict__ pre_w1,  // (4,2)
    const float* __restrict__ pre_b1,  // (4,)
    const float* __restrict__ pre_w2,  // (2,4)
    const float* __restrict__ pre_b2,  // (2,)
    const float* __restrict__ table,   // (TN*TN,)
    float* __restrict__ out,           // (B,)
    int nbatch)
{
    float w1[8], b1[4], w2[8], b2[2];
#pragma unroll
    for (int i = 0; i < 8; i++) w1[i] = pre_w1[i];
#pragma unroll
    for (int i = 0; i < 4; i++) b1[i] = pre_b1[i];
#pragma unroll
    for (int i = 0; i < 8; i++) w2[i] = pre_w2[i];
#pragma unroll
    for (int i = 0; i < 2; i++) b2[i] = pre_b2[i];

    float B0, B1;
    u_bounds(w2, b2, B0, B1);
    float sc0 = (float)(TN - 1) / (2.0f * B0);
    float sc1 = (float)(TN - 1) / (2.0f * B1);

    int base = (blockIdx.x * blockDim.x + threadIdx.x) * 4;
    if (base >= nbatch) return;

    float4 xa = *reinterpret_cast<const float4*>(x + 2 * (long long)base);
    float4 xb = *reinterpret_cast<const float4*>(x + 2 * (long long)base + 4);
    float xs0[4] = { xa.x, xa.z, xb.x, xb.z };
    float xs1[4] = { xa.y, xa.w, xb.y, xb.w };
    float res[4];

#pragma unroll
    for (int t = 0; t < 4; t++) {
        float x0 = xs0[t], x1 = xs1[t];

        float h0 = ftanh(fmaf(w1[0], x0, fmaf(w1[1], x1, b1[0])));
        float h1 = ftanh(fmaf(w1[2], x0, fmaf(w1[3], x1, b1[1])));
        float h2 = ftanh(fmaf(w1[4], x0, fmaf(w1[5], x1, b1[2])));
        float h3 = ftanh(fmaf(w1[6], x0, fmaf(w1[7], x1, b1[3])));

        float u0 = fmaf(w2[0], h0, fmaf(w2[1], h1, fmaf(w2[2], h2, fmaf(w2[3], h3, b2[0]))));
        float u1 = fmaf(w2[4], h0, fmaf(w2[5], h1, fmaf(w2[6], h2, fmaf(w2[7], h3, b2[1]))));

        float t0 = (u0 + B0) * sc0;
        float t1 = (u1 + B1) * sc1;
        t0 = fminf(fmaxf(t0, 0.0f), (float)(TN - 1));
        t1 = fminf(fmaxf(t1, 0.0f), (float)(TN - 1));
        float i0f = fminf(floorf(t0), (float)(TN - 2));
        float j0f = fminf(floorf(t1), (float)(TN - 2));
        float f0 = t0 - i0f;
        float f1 = t1 - j0f;
        int i0 = (int)i0f;
        int j0 = (int)j0f;

        const float* p = table + j0 * TN + i0;
        float a = p[0], b = p[1], c = p[TN], d = p[TN + 1];
        float top = fmaf(f0, b - a, a);
        float bot = fmaf(f0, d - c, c);
        res[t] = fmaf(f1, bot - top, top);
    }

    // streamed once, never re-read: nontemporal so it doesn't evict the table
    vfloat4 r4 = { res[0], res[1], res[2], res[3] };
    __builtin_nontemporal_store(r4, reinterpret_cast<vfloat4*>(out + base));
}

extern "C" void kernel_launch(void* const* d_in, const int* in_sizes, int n_in,
                              void* d_out, int out_size, void* d_ws, size_t ws_size,
                              hipStream_t stream) {
    const float* x      = (const float*)d_in[0];
    const float* pre_w1 = (const float*)d_in[1];
    const float* pre_b1 = (const float*)d_in[2];
    const float* pre_w2 = (const float*)d_in[3];
    const float* pre_b2 = (const float*)d_in[4];
    const float* qw     = (const float*)d_in[5];
    const float* post_w = (const float*)d_in[6];
    const float* post_b = (const float*)d_in[7];
    float* out   = (float*)d_out;
    float* table = (float*)d_ws;   // TN*TN floats = 64 KB

    // 1) table build (d_ws re-poisoned every call, so rebuild every call)
    hipLaunchKernelGGL(build_table, dim3((TN * TN) / 256), dim3(256), 0, stream,
                       qw, pre_w2, pre_b2, post_w, post_b, table);

    // 2) MLP layer 1 + bilinear lookup, 4 samples/thread
    int nbatch  = in_sizes[0] / 2;
    int threads = 256;
    int spb     = threads * 4;
    int blocks  = (nbatch + spb - 1) / spb;
    hipLaunchKernelGGL(eval_kernel, dim3(blocks), dim3(threads), 0, stream,
                       x, pre_w1, pre_b1, pre_w2, pre_b2, table, out, nbatch);
}